// Round 1
// baseline (767.737 us; speedup 1.0000x reference)
//
#include <hip/hip_runtime.h>

#define T_STEPS 12
#define B_SZ 8
#define N_NODES 4000
#define NCOLS 192   // B*T*C

// ---------------- K1: pack x -> XMAT[4000][192]; transpose W -> Wt[128][256]
__global__ __launch_bounds__(256) void prep_kernel(
    const float* __restrict__ x, const float* __restrict__ W_ih,
    const float* __restrict__ W_hh, float* __restrict__ XMAT,
    float* __restrict__ Wt) {
  int idx = blockIdx.x * 256 + threadIdx.x;
  if (idx < N_NODES * NCOLS) {
    int m = idx / NCOLS;
    int j = idx - m * NCOLS;
    int b = j / (T_STEPS * 2);
    int r = j - b * (T_STEPS * 2);
    int t = r >> 1;
    int c = r & 1;
    XMAT[idx] = x[((b * T_STEPS + t) * N_NODES + m) * 2 + c];
  } else {
    int widx = idx - N_NODES * NCOLS;   // exactly 128*256 of these
    int k = widx >> 8;
    int j = widx & 255;
    Wt[widx] = (k < 64) ? W_ih[j * 64 + k] : W_hh[j * 64 + (k - 64)];
  }
}

// ---------------- K2: XGT[j][n] = sum_m adj[n][m] * XMAT[m][j]
// M=4000 rows(n), N=192 cols(j), K=4000. BM=64 BN=64 BK=32, 4x4 micro.
__global__ __launch_bounds__(256) void gcn_gemm_kernel(
    const float* __restrict__ adj, const float* __restrict__ XMAT,
    float* __restrict__ XGT) {
  __shared__ float As[32 * 68];  // [kk][row] padded stride 68
  __shared__ float Bs[32 * 64];  // [kk][col]
  int tid = threadIdx.x;
  int row0 = blockIdx.x * 64;
  int col0 = blockIdx.y * 64;
  int tr = tid & 15;
  int tc = tid >> 4;
  float acc[4][4];
#pragma unroll
  for (int i = 0; i < 4; i++)
#pragma unroll
    for (int j = 0; j < 4; j++) acc[i][j] = 0.f;

  for (int kt = 0; kt < 4000; kt += 32) {
    __syncthreads();
#pragma unroll
    for (int l = 0; l < 2; l++) {   // stage A (transposed): 64 rows x 32 k
      int idx4 = tid * 2 + l;       // 0..511
      int i = idx4 >> 3;            // row 0..63
      int kk4 = idx4 & 7;           // k-quad 0..7
      float4 v = make_float4(0.f, 0.f, 0.f, 0.f);
      int grow = row0 + i;
      if (grow < N_NODES)
        v = *reinterpret_cast<const float4*>(&adj[(size_t)grow * 4000 + kt + kk4 * 4]);
      As[(kk4 * 4 + 0) * 68 + i] = v.x;
      As[(kk4 * 4 + 1) * 68 + i] = v.y;
      As[(kk4 * 4 + 2) * 68 + i] = v.z;
      As[(kk4 * 4 + 3) * 68 + i] = v.w;
    }
#pragma unroll
    for (int l = 0; l < 2; l++) {   // stage B: 32 k x 64 j
      int idx4 = tid * 2 + l;
      int kk = idx4 >> 4;
      int j4 = idx4 & 15;
      float4 v = *reinterpret_cast<const float4*>(&XMAT[(kt + kk) * NCOLS + col0 + j4 * 4]);
      *reinterpret_cast<float4*>(&Bs[kk * 64 + j4 * 4]) = v;
    }
    __syncthreads();
#pragma unroll
    for (int kk = 0; kk < 32; kk++) {
      float4 a = *reinterpret_cast<const float4*>(&As[kk * 68 + tr * 4]);
      float4 b = *reinterpret_cast<const float4*>(&Bs[kk * 64 + tc * 4]);
      float av[4] = {a.x, a.y, a.z, a.w};
      float bv[4] = {b.x, b.y, b.z, b.w};
#pragma unroll
      for (int i = 0; i < 4; i++)
#pragma unroll
        for (int j = 0; j < 4; j++) acc[i][j] += av[i] * bv[j];
    }
  }
#pragma unroll
  for (int i = 0; i < 4; i++) {
    int grow = row0 + tr * 4 + i;
    if (grow < N_NODES) {
#pragma unroll
      for (int j = 0; j < 4; j++)
        XGT[(col0 + tc * 4 + j) * N_NODES + grow] = acc[i][j];
    }
  }
}

// ---------------- K3: persistent-row fused GCN-linear + LSTM + output proj
__device__ __forceinline__ float sigmoid_f(float x) {
  return __fdividef(1.f, 1.f + __expf(-x));
}
__device__ __forceinline__ float tanh_f(float x) {
  float xc = fminf(fmaxf(x, -15.f), 15.f);
  float e = __expf(2.f * xc);
  return __fdividef(e - 1.f, e + 1.f);
}

__global__ __launch_bounds__(256, 3) void lstm_kernel(
    const float* __restrict__ XGT, const float* __restrict__ Wt,
    const float* __restrict__ W_gcn, const float* __restrict__ b_gcn,
    const float* __restrict__ b_ih, const float* __restrict__ b_hh,
    const float* __restrict__ W_out, const float* __restrict__ b_out,
    float* __restrict__ out) {
  __shared__ float Wl[32 * 256];   // one K-chunk of Wt, [kk][j]
  __shared__ float As[128 * 36];   // input matrix [k][row], rows stride 36; k<64: g, k>=64: h
  __shared__ float biasL[256];
  __shared__ float WgL[128];
  __shared__ float bgL[64];
  __shared__ float WoutL[64];
  __shared__ float red[8 * 32];

  int tid = threadIdx.x;
  int r0 = blockIdx.x * 32;        // 1000 blocks x 32 rows = 32000
  int bb = r0 / N_NODES;           // whole block shares one batch index
  int n0 = r0 - bb * N_NODES;

  // phase 0
  biasL[tid] = b_ih[tid] + b_hh[tid];
  if (tid < 128) WgL[tid] = W_gcn[tid];
  if (tid < 64) bgL[tid] = b_gcn[tid];
  if (tid < 64) WoutL[tid] = W_out[tid];
#pragma unroll
  for (int i = 0; i < 18; i++) As[tid + i * 256] = 0.f;   // 128*36 = 4608 exact
  float creg[8];
#pragma unroll
  for (int i = 0; i < 8; i++) creg[i] = 0.f;
  __syncthreads();

  int rg = tid & 31;               // row for g-phase / output
  int k8 = tid >> 5;               // 0..7
  int tr = tid & 7;                // gemm row-group: rows tr*4..+4
  int tj = tid >> 3;               // 0..31
  int h0 = tj * 2;                 // owns hidx {h0, h0+1} across all 4 gates

  for (int t = 0; t < T_STEPS; t++) {
    // --- g-phase: As[k][rg] = relu(W_gcn @ xg + b_gcn), k<64
    {
      int jcol = (bb * T_STEPS + t) * 2;
      float xg0 = XGT[jcol * N_NODES + n0 + rg];
      float xg1 = XGT[(jcol + 1) * N_NODES + n0 + rg];
#pragma unroll
      for (int i = 0; i < 8; i++) {
        int k = k8 * 8 + i;
        float g = fmaxf(xg0 * WgL[2 * k] + xg1 * WgL[2 * k + 1] + bgL[k], 0.f);
        As[k * 36 + rg] = g;
      }
    }
    // --- gates GEMM: [32 rows x 128 k] x [128 k x 256 j]
    float acc[4][8];
#pragma unroll
    for (int i = 0; i < 4; i++)
#pragma unroll
      for (int q = 0; q < 8; q++) acc[i][q] = 0.f;

    for (int kc = 0; kc < 4; kc++) {
      __syncthreads();             // prev chunk done reading Wl; As writes visible
#pragma unroll
      for (int i = 0; i < 8; i++) {   // stage 32KB W chunk
        int a4 = tid + i * 256;
        *reinterpret_cast<float4*>(&Wl[a4 * 4]) =
            *reinterpret_cast<const float4*>(&Wt[kc * 8192 + a4 * 4]);
      }
      __syncthreads();
#pragma unroll
      for (int kk = 0; kk < 32; kk++) {
        int k = kc * 32 + kk;
        float4 a = *reinterpret_cast<const float4*>(&As[k * 36 + tr * 4]);
        float av[4] = {a.x, a.y, a.z, a.w};
        const float* wrow = &Wl[kk * 256];
        float2 w0 = *reinterpret_cast<const float2*>(&wrow[h0]);
        float2 w1 = *reinterpret_cast<const float2*>(&wrow[h0 + 64]);
        float2 w2 = *reinterpret_cast<const float2*>(&wrow[h0 + 128]);
        float2 w3 = *reinterpret_cast<const float2*>(&wrow[h0 + 192]);
        float wv[8] = {w0.x, w0.y, w1.x, w1.y, w2.x, w2.y, w3.x, w3.y};
#pragma unroll
        for (int i = 0; i < 4; i++)
#pragma unroll
          for (int q = 0; q < 8; q++) acc[i][q] += av[i] * wv[q];
      }
    }
    __syncthreads();               // all GEMM reads of As done before h overwrite
    // --- gate nonlinearity + state update (each thread owns full i,f,g,o quads)
#pragma unroll
    for (int ri = 0; ri < 4; ri++) {
      int r = tr * 4 + ri;
#pragma unroll
      for (int e = 0; e < 2; e++) {
        int hidx = h0 + e;
        float gi = acc[ri][0 + e] + biasL[hidx];
        float gf = acc[ri][2 + e] + biasL[64 + hidx];
        float gg = acc[ri][4 + e] + biasL[128 + hidx];
        float go = acc[ri][6 + e] + biasL[192 + hidx];
        float c = sigmoid_f(gf) * creg[ri * 2 + e] + sigmoid_f(gi) * tanh_f(gg);
        creg[ri * 2 + e] = c;
        As[(64 + hidx) * 36 + r] = sigmoid_f(go) * tanh_f(c);  // h
      }
    }
    // next iteration: g-phase writes k<64 (disjoint); barrier at kc=0 covers h visibility
  }
  __syncthreads();
  // --- output projection: out[row] = h . W_out + b_out
  {
    float partial = 0.f;
#pragma unroll
    for (int i = 0; i < 8; i++) {
      int k = k8 * 8 + i;
      partial += As[(64 + k) * 36 + rg] * WoutL[k];
    }
    red[k8 * 32 + rg] = partial;
  }
  __syncthreads();
  if (tid < 32) {
    float s = b_out[0];
#pragma unroll
    for (int i = 0; i < 8; i++) s += red[i * 32 + tid];
    out[r0 + tid] = s;
  }
}

extern "C" void kernel_launch(void* const* d_in, const int* in_sizes, int n_in,
                              void* d_out, int out_size, void* d_ws, size_t ws_size,
                              hipStream_t stream) {
  const float* x     = (const float*)d_in[0];
  const float* adj   = (const float*)d_in[1];
  const float* W_gcn = (const float*)d_in[2];
  const float* b_gcn = (const float*)d_in[3];
  const float* W_ih  = (const float*)d_in[4];
  const float* W_hh  = (const float*)d_in[5];
  const float* b_ih  = (const float*)d_in[6];
  const float* b_hh  = (const float*)d_in[7];
  const float* W_out = (const float*)d_in[8];
  const float* b_out = (const float*)d_in[9];
  float* outp = (float*)d_out;

  float* XMAT = (float*)d_ws;       // 768000 f
  float* XGT  = XMAT + 768000;      // 768000 f
  float* Wt   = XGT + 768000;       // 32768 f

  prep_kernel<<<3128, 256, 0, stream>>>(x, W_ih, W_hh, XMAT, Wt);
  gcn_gemm_kernel<<<dim3(63, 3), 256, 0, stream>>>(adj, XMAT, XGT);
  lstm_kernel<<<1000, 256, 0, stream>>>(XGT, Wt, W_gcn, b_gcn, b_ih, b_hh,
                                        W_out, b_out, outp);
}

// Round 2
// 292.751 us; speedup vs baseline: 2.6225x; 2.6225x over previous
//
#include <hip/hip_runtime.h>

typedef _Float16 half8 __attribute__((ext_vector_type(8)));
typedef short short8v __attribute__((ext_vector_type(8)));
typedef unsigned short ushort4v __attribute__((ext_vector_type(4)));
typedef float floatx4 __attribute__((ext_vector_type(4)));

#define ASTRIDE 136   // 128 + 8 pad (bf16/f16 elems) -> 272B row stride, 16B aligned

__device__ __forceinline__ unsigned short f2bf(float f) {
  unsigned int u = __float_as_uint(f);
  unsigned int r = (u + 0x7FFFu + ((u >> 16) & 1u)) >> 16;
  return (unsigned short)r;
}
__device__ __forceinline__ float sigf(float x) {
  return 1.f / (1.f + __expf(-x));
}
__device__ __forceinline__ float tanhf_(float x) {
  float xc = fminf(fmaxf(x, -15.f), 15.f);
  float e = __expf(2.f * xc);
  return (e - 1.f) / (e + 1.f);
}

// ---------------- K1: XBT[j][m] = bf16(x), j = b*24+t*2+c, m padded to 4032 (zeros);
//                      Wt2[j][k] = f16([W_ih | W_hh][j][k])
__global__ __launch_bounds__(256) void prep_kernel(
    const float* __restrict__ x, const float* __restrict__ W_ih,
    const float* __restrict__ W_hh, unsigned short* __restrict__ XBT,
    unsigned short* __restrict__ Wt2) {
  int idx = blockIdx.x * 256 + threadIdx.x;
  if (idx < 192 * 4032) {
    int j = idx / 4032;
    int m = idx - j * 4032;
    unsigned short v = 0;
    if (m < 4000) {
      int b = j / 24, r = j - b * 24;
      int t = r >> 1, c = r & 1;
      v = f2bf(x[((b * 12 + t) * 4000 + m) * 2 + c]);
    }
    XBT[idx] = v;
  } else {
    int widx = idx - 192 * 4032;   // exactly 256*128
    int j = widx >> 7, k = widx & 127;
    float val = (k < 64) ? W_ih[j * 64 + k] : W_hh[j * 64 + (k - 64)];
    _Float16 h = (_Float16)val;
    Wt2[widx] = __builtin_bit_cast(unsigned short, h);
  }
}

// ---------------- K2: XGT[j][n] = sum_m adj[n][m] * x[m][j]  (bf16 MFMA)
// grid (3 jblk, 63 nblk), 256 thr = 4 waves (2x2 of 32x32), BK=64
__global__ __launch_bounds__(256, 2) void gcn_gemm_kernel(
    const float* __restrict__ adj, const unsigned short* __restrict__ XBT,
    float* __restrict__ XGT) {
  __shared__ unsigned short Aa[64 * 72];  // [n][m] bf16
  __shared__ unsigned short Bb[64 * 72];  // [j][m] bf16
  int tid = threadIdx.x;
  int w = tid >> 6, lane = tid & 63, l15 = lane & 15, kg = lane >> 4;
  int wr = w >> 1, wc = w & 1;
  int n0 = blockIdx.y * 64;
  int j0 = blockIdx.x * 64;
  int sn = tid >> 2;   // staging row 0..63
  int smq = tid & 3;   // m-quad

  floatx4 acc[2][2];
#pragma unroll
  for (int rt = 0; rt < 2; rt++)
#pragma unroll
    for (int ct = 0; ct < 2; ct++) acc[rt][ct] = {0.f, 0.f, 0.f, 0.f};

  for (int kt = 0; kt < 4032; kt += 64) {
    // stage A: adj fp32 -> bf16
    {
      int ng = n0 + sn;
      bool nok = ng < 4000;
#pragma unroll
      for (int q = 0; q < 4; q++) {
        int ml = smq * 16 + q * 4;
        int mg = kt + ml;
        float4 v = make_float4(0.f, 0.f, 0.f, 0.f);
        if (nok && mg < 4000)
          v = *reinterpret_cast<const float4*>(&adj[(size_t)ng * 4000 + mg]);
        ushort4v sv;
        sv[0] = f2bf(v.x); sv[1] = f2bf(v.y); sv[2] = f2bf(v.z); sv[3] = f2bf(v.w);
        *reinterpret_cast<ushort4v*>(&Aa[sn * 72 + ml]) = sv;
      }
    }
    // stage B: XBT already bf16, pad handles K-tail
#pragma unroll
    for (int q = 0; q < 2; q++) {
      int ml = smq * 16 + q * 8;
      *reinterpret_cast<short8v*>(&Bb[sn * 72 + ml]) =
          *reinterpret_cast<const short8v*>(&XBT[(size_t)(j0 + sn) * 4032 + kt + ml]);
    }
    __syncthreads();
#pragma unroll
    for (int ks = 0; ks < 2; ks++) {
      short8v af[2], bfr[2];
#pragma unroll
      for (int rt = 0; rt < 2; rt++)
        af[rt] = *reinterpret_cast<const short8v*>(
            &Aa[(wr * 32 + rt * 16 + l15) * 72 + ks * 32 + kg * 8]);
#pragma unroll
      for (int ct = 0; ct < 2; ct++)
        bfr[ct] = *reinterpret_cast<const short8v*>(
            &Bb[(wc * 32 + ct * 16 + l15) * 72 + ks * 32 + kg * 8]);
#pragma unroll
      for (int rt = 0; rt < 2; rt++)
#pragma unroll
        for (int ct = 0; ct < 2; ct++)
          acc[rt][ct] = __builtin_amdgcn_mfma_f32_16x16x32_bf16(
              af[rt], bfr[ct], acc[rt][ct], 0, 0, 0);
    }
    __syncthreads();
  }
#pragma unroll
  for (int rt = 0; rt < 2; rt++)
#pragma unroll
    for (int ct = 0; ct < 2; ct++)
#pragma unroll
      for (int e = 0; e < 4; e++) {
        int n = n0 + wr * 32 + rt * 16 + kg * 4 + e;
        int j = j0 + wc * 32 + ct * 16 + l15;
        if (n < 4000) XGT[(size_t)j * 4000 + n] = acc[rt][ct][e];
      }
}

// ---------------- K3: persistent LSTM, f16 MFMA 2-mult (A hi/lo split, lo scaled 1024)
// 500 blocks x 64 rows; wave w owns hidx [w*16, w*16+16) across all 4 gates.
__global__ __launch_bounds__(256, 2) void lstm_kernel(
    const float* __restrict__ XGT, const unsigned short* __restrict__ Wt2,
    const float* __restrict__ W_gcn, const float* __restrict__ b_gcn,
    const float* __restrict__ b_ih, const float* __restrict__ b_hh,
    const float* __restrict__ W_out, const float* __restrict__ b_out,
    float* __restrict__ out) {
  __shared__ unsigned short Ahi[64 * ASTRIDE];  // [row][k] f16; k<64: g, k>=64: h
  __shared__ unsigned short Alo[64 * ASTRIDE];  // scaled-lo (x1024) f16
  __shared__ float xga[24 * 64];                // [t*2+c][row]
  __shared__ float red[4 * 64];

  int tid = threadIdx.x;
  int w = tid >> 6;
  int lane = tid & 63;
  int l15 = lane & 15;
  int kg = lane >> 4;
  int r0 = blockIdx.x * 64;
  int hidx = w * 16 + l15;

  // W fragments resident in VGPRs for the whole kernel (64 VGPRs)
  half8 wf[4][4];
#pragma unroll
  for (int ct = 0; ct < 4; ct++) {
    int j = ct * 64 + hidx;
#pragma unroll
    for (int ks = 0; ks < 4; ks++)
      wf[ct][ks] = *reinterpret_cast<const half8*>(&Wt2[j * 128 + ks * 32 + kg * 8]);
  }
  float bI = b_ih[hidx] + b_hh[hidx];
  float bF = b_ih[64 + hidx] + b_hh[64 + hidx];
  float bG = b_ih[128 + hidx] + b_hh[128 + hidx];
  float bO = b_ih[192 + hidx] + b_hh[192 + hidx];
  float wg0 = W_gcn[2 * hidx], wg1 = W_gcn[2 * hidx + 1], bg = b_gcn[hidx];

  // zero A (h region must start 0; pad too)
  for (int i = tid; i < 64 * ASTRIDE / 2; i += 256) {
    reinterpret_cast<unsigned int*>(Ahi)[i] = 0u;
    reinterpret_cast<unsigned int*>(Alo)[i] = 0u;
  }
  // preload all timesteps' xg
  for (int i = tid; i < 24 * 64; i += 256) {
    int row = i & 63, tc = i >> 6;
    int g = r0 + row;
    int b = g / 4000, n = g - b * 4000;
    xga[i] = XGT[(size_t)(b * 24 + tc) * 4000 + n];
  }
  float creg[16];
#pragma unroll
  for (int i = 0; i < 16; i++) creg[i] = 0.f;
  __syncthreads();

  for (int t = 0; t < 12; t++) {
    // --- g-phase: write GCN-relu outputs into A[k<64]
#pragma unroll
    for (int rt = 0; rt < 4; rt++)
#pragma unroll
      for (int rr = 0; rr < 4; rr++) {
        int row = rt * 16 + kg * 4 + rr;
        float xg0 = xga[(t * 2) * 64 + row];
        float xg1 = xga[(t * 2 + 1) * 64 + row];
        float gv = fmaxf(xg0 * wg0 + xg1 * wg1 + bg, 0.f);
        _Float16 hi = (_Float16)gv;
        _Float16 lo = (_Float16)((gv - (float)hi) * 1024.f);
        Ahi[row * ASTRIDE + hidx] = __builtin_bit_cast(unsigned short, hi);
        Alo[row * ASTRIDE + hidx] = __builtin_bit_cast(unsigned short, lo);
      }
    __syncthreads();

    // --- gates GEMM: [64 x 128] @ [128 x 256], f16 2-mult
    floatx4 acc[4][4];
#pragma unroll
    for (int rt = 0; rt < 4; rt++)
#pragma unroll
      for (int ct = 0; ct < 4; ct++) acc[rt][ct] = {0.f, 0.f, 0.f, 0.f};

#pragma unroll
    for (int rt = 0; rt < 4; rt++) {
      const half8* ph = reinterpret_cast<const half8*>(&Ahi[(rt * 16 + l15) * ASTRIDE]);
      const half8* pl = reinterpret_cast<const half8*>(&Alo[(rt * 16 + l15) * ASTRIDE]);
      half8 ah[4], al[4];
#pragma unroll
      for (int ks = 0; ks < 4; ks++) {
        ah[ks] = ph[ks * 4 + kg];
        al[ks] = pl[ks * 4 + kg];
      }
#pragma unroll
      for (int ks = 0; ks < 4; ks++)
#pragma unroll
        for (int ct = 0; ct < 4; ct++)
          acc[rt][ct] = __builtin_amdgcn_mfma_f32_16x16x32_f16(
              ah[ks], wf[ct][ks], acc[rt][ct], 0, 0, 0);
      floatx4 tmp[4];
#pragma unroll
      for (int ct = 0; ct < 4; ct++) tmp[ct] = {0.f, 0.f, 0.f, 0.f};
#pragma unroll
      for (int ks = 0; ks < 4; ks++)
#pragma unroll
        for (int ct = 0; ct < 4; ct++)
          tmp[ct] = __builtin_amdgcn_mfma_f32_16x16x32_f16(
              al[ks], wf[ct][ks], tmp[ct], 0, 0, 0);
#pragma unroll
      for (int ct = 0; ct < 4; ct++)
#pragma unroll
        for (int e = 0; e < 4; e++)
          acc[rt][ct][e] += tmp[ct][e] * (1.f / 1024.f);
    }
    __syncthreads();  // all waves done reading A before h overwrite

    // --- epilogue: thread-local gate quads, c in regs, h -> A[k>=64]
#pragma unroll
    for (int rt = 0; rt < 4; rt++)
#pragma unroll
      for (int rr = 0; rr < 4; rr++) {
        int row = rt * 16 + kg * 4 + rr;
        float gi = acc[rt][0][rr] + bI;
        float gf = acc[rt][1][rr] + bF;
        float gg = acc[rt][2][rr] + bG;
        float go = acc[rt][3][rr] + bO;
        float c = sigf(gf) * creg[rt * 4 + rr] + sigf(gi) * tanhf_(gg);
        creg[rt * 4 + rr] = c;
        float h = sigf(go) * tanhf_(c);
        _Float16 hi = (_Float16)h;
        _Float16 lo = (_Float16)((h - (float)hi) * 1024.f);
        Ahi[row * ASTRIDE + 64 + hidx] = __builtin_bit_cast(unsigned short, hi);
        Alo[row * ASTRIDE + 64 + hidx] = __builtin_bit_cast(unsigned short, lo);
      }
  }
  __syncthreads();

  // --- output projection
  {
    int rg = tid & 63, kq = tid >> 6;
    float partial = 0.f;
#pragma unroll
    for (int i = 0; i < 16; i++) {
      int k = kq * 16 + i;
      float hv = (float)__builtin_bit_cast(_Float16, Ahi[rg * ASTRIDE + 64 + k]) +
                 (float)__builtin_bit_cast(_Float16, Alo[rg * ASTRIDE + 64 + k]) * (1.f / 1024.f);
      partial += hv * W_out[k];
    }
    red[kq * 64 + rg] = partial;
  }
  __syncthreads();
  if (tid < 64) {
    float s = b_out[0] + red[tid] + red[64 + tid] + red[128 + tid] + red[192 + tid];
    out[r0 + tid] = s;
  }
}

extern "C" void kernel_launch(void* const* d_in, const int* in_sizes, int n_in,
                              void* d_out, int out_size, void* d_ws, size_t ws_size,
                              hipStream_t stream) {
  const float* x     = (const float*)d_in[0];
  const float* adj   = (const float*)d_in[1];
  const float* W_gcn = (const float*)d_in[2];
  const float* b_gcn = (const float*)d_in[3];
  const float* W_ih  = (const float*)d_in[4];
  const float* W_hh  = (const float*)d_in[5];
  const float* b_ih  = (const float*)d_in[6];
  const float* b_hh  = (const float*)d_in[7];
  const float* W_out = (const float*)d_in[8];
  const float* b_out = (const float*)d_in[9];
  float* outp = (float*)d_out;

  // ws layout (all 16B aligned):
  float* XGT = (float*)d_ws;                                      // 192*4000 f32 = 3,072,000 B
  unsigned short* XBT = (unsigned short*)((char*)d_ws + 3072000); // 192*4032 bf16 = 1,548,288 B
  unsigned short* Wt2 = (unsigned short*)((char*)d_ws + 4620288); // 256*128 f16 = 65,536 B

  prep_kernel<<<3152, 256, 0, stream>>>(x, W_ih, W_hh, XBT, Wt2);
  gcn_gemm_kernel<<<dim3(3, 63), 256, 0, stream>>>(adj, XBT, XGT);
  lstm_kernel<<<500, 256, 0, stream>>>(XGT, Wt2, W_gcn, b_gcn, b_ih, b_hh,
                                       W_out, b_out, outp);
}

// Round 3
// 215.890 us; speedup vs baseline: 3.5561x; 1.3560x over previous
//
#include <hip/hip_runtime.h>

typedef _Float16 half8 __attribute__((ext_vector_type(8)));
typedef short short8v __attribute__((ext_vector_type(8)));
typedef float floatx4 __attribute__((ext_vector_type(4)));

#define GLOBAL_AS __attribute__((address_space(1)))
#define LDS_AS __attribute__((address_space(3)))

__device__ __forceinline__ unsigned short f2bf(float f) {
  unsigned int u = __float_as_uint(f);
  unsigned int r = (u + 0x7FFFu + ((u >> 16) & 1u)) >> 16;
  return (unsigned short)r;
}
__device__ __forceinline__ float sigf(float x) {
  return __builtin_amdgcn_rcpf(1.f + __expf(-x));
}
__device__ __forceinline__ float tanhf_(float x) {
  return 1.f - 2.f * __builtin_amdgcn_rcpf(1.f + __expf(2.f * x));
}

// ---------------- K1: XBT[j][m] bf16 (m padded to 4032 w/ zeros); Wt2[j][k] f16
__global__ __launch_bounds__(256) void prep_kernel(
    const float* __restrict__ x, const float* __restrict__ W_ih,
    const float* __restrict__ W_hh, unsigned short* __restrict__ XBT,
    unsigned short* __restrict__ Wt2) {
  int idx = blockIdx.x * 256 + threadIdx.x;
  if (idx < 192 * 4032) {
    int j = idx / 4032;
    int m = idx - j * 4032;
    unsigned short v = 0;
    if (m < 4000) {
      int b = j / 24, r = j - b * 24;
      int t = r >> 1, c = r & 1;
      v = f2bf(x[((b * 12 + t) * 4000 + m) * 2 + c]);
    }
    XBT[idx] = v;
  } else {
    int widx = idx - 192 * 4032;   // exactly 256*128
    int j = widx >> 7, k = widx & 127;
    float val = (k < 64) ? W_ih[j * 64 + k] : W_hh[j * 64 + (k - 64)];
    _Float16 h = (_Float16)val;
    Wt2[widx] = __builtin_bit_cast(unsigned short, h);
  }
}

// ---------------- K2: XGT[j][n] = sum_m adj[n][m]*x[m][j], bf16 MFMA,
// 250 blocks x (16 n-rows x 192 j), dbuf global_load_lds, counted vmcnt.
__global__ __launch_bounds__(256, 2) void gcn_gemm_kernel(
    const float* __restrict__ adj, const unsigned short* __restrict__ XBT,
    float* __restrict__ XGT) {
  __shared__ float Ab[2][1024];             // [row 16][64 f32], granule-swizzled
  __shared__ unsigned short Bb[2][12288];   // [j 192][64 f16], granule-swizzled
  int tid = threadIdx.x;
  int w = tid >> 6, lane = tid & 63, l15 = lane & 15, kg = lane >> 4;
  int n0 = blockIdx.x * 16;

  // ---- staging geometry (source pre-XORed so linear LDS dest + XOR reads work)
  int a_row = (w << 2) + (lane >> 4);
  int a_g = lane & 15;
  int a_gx = (a_g & 8) | ((a_g ^ a_row) & 7);
  const float* aSrc = adj + (size_t)(n0 + a_row) * 4000 + (a_gx << 2);
  const float* aSrcT = adj + (size_t)(n0 + a_row) * 4000 + 3968 +
                       ((a_g < 8) ? (((a_g ^ a_row) & 7) << 2) : 0);
  const unsigned short* bSrc[6];
  int bj[6];
#pragma unroll
  for (int q = 0; q < 6; q++) {
    int ib = w * 6 + q;
    int j = ib * 8 + (lane >> 3);
    int g = lane & 7;
    bj[q] = ib * 512;
    bSrc[q] = XBT + (size_t)j * 4032 + ((g ^ (j & 7)) << 3);
  }

#define STAGE_K2(kt, buf)                                                      \
  {                                                                            \
    __builtin_amdgcn_global_load_lds((const GLOBAL_AS unsigned int*)(aSrc + (kt)), \
        (LDS_AS unsigned int*)&Ab[(buf)][w * 256], 16, 0, 0);                  \
    _Pragma("unroll")                                                          \
    for (int q = 0; q < 6; q++)                                                \
      __builtin_amdgcn_global_load_lds((const GLOBAL_AS unsigned int*)(bSrc[q] + (kt)), \
          (LDS_AS unsigned int*)&Bb[(buf)][bj[q]], 16, 0, 0);                  \
  }
#define STAGE_K2T(buf)                                                         \
  {                                                                            \
    __builtin_amdgcn_global_load_lds((const GLOBAL_AS unsigned int*)(aSrcT),   \
        (LDS_AS unsigned int*)&Ab[(buf)][w * 256], 16, 0, 0);                  \
    _Pragma("unroll")                                                          \
    for (int q = 0; q < 6; q++)                                                \
      __builtin_amdgcn_global_load_lds((const GLOBAL_AS unsigned int*)(bSrc[q] + 3968), \
          (LDS_AS unsigned int*)&Bb[(buf)][bj[q]], 16, 0, 0);                  \
  }

  floatx4 acc[3];
  acc[0] = acc[1] = acc[2] = floatx4{0.f, 0.f, 0.f, 0.f};
  int rowA = l15;
  int xA = (rowA & 7) << 2;   // f32-index XOR (granule)
  int jb[3], xB[3];
#pragma unroll
  for (int ct = 0; ct < 3; ct++) {
    int j = w * 48 + ct * 16 + l15;
    jb[ct] = j * 64;
    xB[ct] = (j & 7) << 3;    // f16-index XOR
  }

  STAGE_K2(0, 0);
  for (int i = 0; i < 62; i++) {
    int cur = i & 1;
    if (i < 61) { STAGE_K2((i + 1) * 64, cur ^ 1); }
    else        { STAGE_K2T(cur ^ 1); }
    asm volatile("s_waitcnt vmcnt(7)" ::: "memory");
    __builtin_amdgcn_s_barrier();
    asm volatile("" ::: "memory");
#pragma unroll
    for (int ks = 0; ks < 2; ks++) {
      int k0 = ks * 32 + kg * 8;
      float4 u = *reinterpret_cast<const float4*>(&Ab[cur][rowA * 64 + (k0 ^ xA)]);
      float4 v = *reinterpret_cast<const float4*>(&Ab[cur][rowA * 64 + ((k0 + 4) ^ xA)]);
      short8v af;
      af[0] = f2bf(u.x); af[1] = f2bf(u.y); af[2] = f2bf(u.z); af[3] = f2bf(u.w);
      af[4] = f2bf(v.x); af[5] = f2bf(v.y); af[6] = f2bf(v.z); af[7] = f2bf(v.w);
#pragma unroll
      for (int ct = 0; ct < 3; ct++) {
        short8v bf = *reinterpret_cast<const short8v*>(&Bb[cur][jb[ct] + (k0 ^ xB[ct])]);
        acc[ct] = __builtin_amdgcn_mfma_f32_16x16x32_bf16(af, bf, acc[ct], 0, 0, 0);
      }
    }
    __builtin_amdgcn_s_barrier();
  }
  // tail tile (32 k) in buf 0, ks=0 only
  asm volatile("s_waitcnt vmcnt(0)" ::: "memory");
  __builtin_amdgcn_s_barrier();
  asm volatile("" ::: "memory");
  {
    int k0 = kg * 8;
    float4 u = *reinterpret_cast<const float4*>(&Ab[0][rowA * 64 + (k0 ^ xA)]);
    float4 v = *reinterpret_cast<const float4*>(&Ab[0][rowA * 64 + ((k0 + 4) ^ xA)]);
    short8v af;
    af[0] = f2bf(u.x); af[1] = f2bf(u.y); af[2] = f2bf(u.z); af[3] = f2bf(u.w);
    af[4] = f2bf(v.x); af[5] = f2bf(v.y); af[6] = f2bf(v.z); af[7] = f2bf(v.w);
#pragma unroll
    for (int ct = 0; ct < 3; ct++) {
      short8v bf = *reinterpret_cast<const short8v*>(&Bb[0][jb[ct] + (k0 ^ xB[ct])]);
      acc[ct] = __builtin_amdgcn_mfma_f32_16x16x32_bf16(af, bf, acc[ct], 0, 0, 0);
    }
  }
#pragma unroll
  for (int ct = 0; ct < 3; ct++) {
    int j = w * 48 + ct * 16 + l15;
#pragma unroll
    for (int e = 0; e < 4; e++) {
      int n = n0 + kg * 4 + e;
      XGT[(size_t)j * 4000 + n] = acc[ct][e];
    }
  }
}

// ---------------- K3: persistent LSTM, single-mult f16 MFMA, 32 rows/block
__global__ __launch_bounds__(256, 3) void lstm_kernel(
    const float* __restrict__ XGT, const unsigned short* __restrict__ Wt2,
    const float* __restrict__ W_gcn, const float* __restrict__ b_gcn,
    const float* __restrict__ b_ih, const float* __restrict__ b_hh,
    const float* __restrict__ W_out, const float* __restrict__ b_out,
    float* __restrict__ out) {
  __shared__ unsigned short A[32 * 128];  // [row][k] f16, XOR-swizzled; k<64: g, k>=64: h
  __shared__ float xga[24 * 32];          // [t*2+c][row]
  __shared__ float red[8 * 32];

  int tid = threadIdx.x;
  int w = tid >> 6, lane = tid & 63, l15 = lane & 15, kg = lane >> 4;
  int r0 = blockIdx.x * 32;
  int hidx = w * 16 + l15;

  // W fragments resident in VGPRs (64 VGPRs)
  half8 wf[4][4];
#pragma unroll
  for (int ct = 0; ct < 4; ct++) {
    int j = ct * 64 + hidx;
#pragma unroll
    for (int ks = 0; ks < 4; ks++)
      wf[ct][ks] = *reinterpret_cast<const half8*>(&Wt2[j * 128 + ks * 32 + kg * 8]);
  }
  float bI = b_ih[hidx] + b_hh[hidx];
  float bF = b_ih[64 + hidx] + b_hh[64 + hidx];
  float bG = b_ih[128 + hidx] + b_hh[128 + hidx];
  float bO = b_ih[192 + hidx] + b_hh[192 + hidx];
  float wg0 = W_gcn[2 * hidx], wg1 = W_gcn[2 * hidx + 1], bg = b_gcn[hidx];

  for (int i = tid; i < 32 * 128 / 2; i += 256)
    reinterpret_cast<unsigned int*>(A)[i] = 0u;
  for (int i = tid; i < 24 * 32; i += 256) {
    int row = i & 31, tc = i >> 5;
    int g = r0 + row;
    int b = g / 4000, n = g - b * 4000;
    xga[i] = XGT[(size_t)(b * 24 + tc) * 4000 + n];
  }
  float creg[8];
#pragma unroll
  for (int i = 0; i < 8; i++) creg[i] = 0.f;
  __syncthreads();

  for (int t = 0; t < 12; t++) {
    // --- g-phase: GCN linear + relu -> A[k<64]
#pragma unroll
    for (int half = 0; half < 2; half++)
#pragma unroll
      for (int rr = 0; rr < 4; rr++) {
        int row = half * 16 + kg * 4 + rr;
        float xg0 = xga[(2 * t) * 32 + row];
        float xg1 = xga[(2 * t + 1) * 32 + row];
        float gv = fmaxf(xg0 * wg0 + xg1 * wg1 + bg, 0.f);
        _Float16 hv = (_Float16)gv;
        A[row * 128 + (hidx ^ ((row & 7) << 3))] = __builtin_bit_cast(unsigned short, hv);
      }
    __syncthreads();

    // --- gates GEMM [32 x 128] @ [128 x 256]
    floatx4 acc[2][4];
#pragma unroll
    for (int rt = 0; rt < 2; rt++)
#pragma unroll
      for (int ct = 0; ct < 4; ct++) acc[rt][ct] = floatx4{0.f, 0.f, 0.f, 0.f};
#pragma unroll
    for (int rt = 0; rt < 2; rt++) {
      int row = rt * 16 + l15;
      int xr = (row & 7) << 3;
      half8 af[4];
#pragma unroll
      for (int ks = 0; ks < 4; ks++)
        af[ks] = *reinterpret_cast<const half8*>(&A[row * 128 + ((ks * 32 + kg * 8) ^ xr)]);
#pragma unroll
      for (int ks = 0; ks < 4; ks++)
#pragma unroll
        for (int ct = 0; ct < 4; ct++)
          acc[rt][ct] = __builtin_amdgcn_mfma_f32_16x16x32_f16(
              af[ks], wf[ct][ks], acc[rt][ct], 0, 0, 0);
    }
    __syncthreads();

    // --- epilogue: thread-local gate quads, c in regs, h -> A[k>=64]
#pragma unroll
    for (int rt = 0; rt < 2; rt++)
#pragma unroll
      for (int e = 0; e < 4; e++) {
        int row = rt * 16 + kg * 4 + e;
        float gi = acc[rt][0][e] + bI;
        float gf = acc[rt][1][e] + bF;
        float gg = acc[rt][2][e] + bG;
        float go = acc[rt][3][e] + bO;
        float c = sigf(gf) * creg[rt * 4 + e] + sigf(gi) * tanhf_(gg);
        creg[rt * 4 + e] = c;
        float h = sigf(go) * tanhf_(c);
        _Float16 hv = (_Float16)h;
        A[row * 128 + ((64 + hidx) ^ ((row & 7) << 3))] = __builtin_bit_cast(unsigned short, hv);
      }
  }
  __syncthreads();

  // --- output projection
  {
    int rg = tid & 31, kq = tid >> 5;
    float partial = 0.f;
#pragma unroll
    for (int i = 0; i < 8; i++) {
      int k = kq * 8 + i;
      float hv = (float)__builtin_bit_cast(
          _Float16, A[rg * 128 + ((64 + k) ^ ((rg & 7) << 3))]);
      partial += hv * W_out[k];
    }
    red[kq * 32 + rg] = partial;
  }
  __syncthreads();
  if (tid < 32) {
    float s = b_out[0];
#pragma unroll
    for (int i = 0; i < 8; i++) s += red[i * 32 + tid];
    out[r0 + tid] = s;
  }
}

extern "C" void kernel_launch(void* const* d_in, const int* in_sizes, int n_in,
                              void* d_out, int out_size, void* d_ws, size_t ws_size,
                              hipStream_t stream) {
  const float* x     = (const float*)d_in[0];
  const float* adj   = (const float*)d_in[1];
  const float* W_gcn = (const float*)d_in[2];
  const float* b_gcn = (const float*)d_in[3];
  const float* W_ih  = (const float*)d_in[4];
  const float* W_hh  = (const float*)d_in[5];
  const float* b_ih  = (const float*)d_in[6];
  const float* b_hh  = (const float*)d_in[7];
  const float* W_out = (const float*)d_in[8];
  const float* b_out = (const float*)d_in[9];
  float* outp = (float*)d_out;

  float* XGT = (float*)d_ws;                                      // 192*4000 f32
  unsigned short* XBT = (unsigned short*)((char*)d_ws + 3072000); // 192*4032 bf16
  unsigned short* Wt2 = (unsigned short*)((char*)d_ws + 4620288); // 256*128 f16

  prep_kernel<<<3152, 256, 0, stream>>>(x, W_ih, W_hh, XBT, Wt2);
  gcn_gemm_kernel<<<250, 256, 0, stream>>>(adj, XBT, XGT);
  lstm_kernel<<<1000, 256, 0, stream>>>(XGT, Wt2, W_gcn, b_gcn, b_ih, b_hh,
                                        W_out, b_out, outp);
}

// Round 4
// 195.935 us; speedup vs baseline: 3.9183x; 1.1018x over previous
//
#include <hip/hip_runtime.h>

typedef _Float16 half8 __attribute__((ext_vector_type(8)));
typedef short short8v __attribute__((ext_vector_type(8)));
typedef unsigned short ushort4v __attribute__((ext_vector_type(4)));
typedef float floatx4 __attribute__((ext_vector_type(4)));

#define GLOBAL_AS __attribute__((address_space(1)))
#define LDS_AS __attribute__((address_space(3)))

__device__ __forceinline__ unsigned short f2bf(float f) {
  unsigned int u = __float_as_uint(f);
  unsigned int r = (u + 0x7FFFu + ((u >> 16) & 1u)) >> 16;
  return (unsigned short)r;
}
__device__ __forceinline__ float sigf(float x) {
  return __builtin_amdgcn_rcpf(1.f + __expf(-x));
}
__device__ __forceinline__ float tanhf_(float x) {
  return 1.f - 2.f * __builtin_amdgcn_rcpf(1.f + __expf(2.f * x));
}

// ---------------- K1 (vectorized): XBT[j][m] bf16 (m pad 4032); Wt2[j][k] f16
// part1: 96 bt-pairs x 1008 m-groups(4 m, both c). part2: 256 j x 16 k-octs.
__global__ __launch_bounds__(256) void prep_kernel(
    const float* __restrict__ x, const float* __restrict__ W_ih,
    const float* __restrict__ W_hh, unsigned short* __restrict__ XBT,
    unsigned short* __restrict__ Wt2) {
  int idx = blockIdx.x * 256 + threadIdx.x;
  if (idx < 96 * 1008) {
    int bt = idx / 1008;
    int mg = idx - bt * 1008;
    int m0 = mg * 4;
    int j0 = bt * 2;
    ushort4v c0, c1;
    if (m0 < 4000) {
      const float* px = x + ((size_t)bt * 4000 + m0) * 2;
      float4 v0 = *reinterpret_cast<const float4*>(px);
      float4 v1 = *reinterpret_cast<const float4*>(px + 4);
      c0[0] = f2bf(v0.x); c0[1] = f2bf(v0.z); c0[2] = f2bf(v1.x); c0[3] = f2bf(v1.z);
      c1[0] = f2bf(v0.y); c1[1] = f2bf(v0.w); c1[2] = f2bf(v1.y); c1[3] = f2bf(v1.w);
    } else {
      c0 = ushort4v{0, 0, 0, 0};
      c1 = ushort4v{0, 0, 0, 0};
    }
    *reinterpret_cast<ushort4v*>(&XBT[(size_t)j0 * 4032 + m0]) = c0;
    *reinterpret_cast<ushort4v*>(&XBT[(size_t)(j0 + 1) * 4032 + m0]) = c1;
  } else {
    int widx = idx - 96 * 1008;   // exactly 256*16
    int j = widx >> 4, kq = widx & 15;
    const float* src = (kq < 8) ? (W_ih + j * 64 + kq * 8)
                                : (W_hh + j * 64 + (kq - 8) * 8);
    float4 v0 = *reinterpret_cast<const float4*>(src);
    float4 v1 = *reinterpret_cast<const float4*>(src + 4);
    half8 h;
    h[0] = (_Float16)v0.x; h[1] = (_Float16)v0.y; h[2] = (_Float16)v0.z; h[3] = (_Float16)v0.w;
    h[4] = (_Float16)v1.x; h[5] = (_Float16)v1.y; h[6] = (_Float16)v1.z; h[7] = (_Float16)v1.w;
    *reinterpret_cast<half8*>(&Wt2[j * 128 + kq * 8]) = h;
  }
}

// ---------------- K2: K-split GCN GEMM. grid = 7 chunks x 250 n-blocks.
// XGP[ch][j][n] partial = sum_{m in chunk} adj[n][m]*x[m][j]
__global__ __launch_bounds__(256, 2) void gcn_gemm_kernel(
    const float* __restrict__ adj, const unsigned short* __restrict__ XBT,
    float* __restrict__ XGP) {
  __shared__ float Ab[2][1024];             // [row 16][64 f32], granule-swizzled
  __shared__ unsigned short Bb[2][12288];   // [j 192][64 f16], granule-swizzled
  int tid = threadIdx.x;
  int w = tid >> 6, lane = tid & 63, l15 = lane & 15, kg = lane >> 4;
  int bid = blockIdx.x;
  int ch = bid / 250;            // 0..6
  int nb = bid - ch * 250;
  int n0 = nb * 16;
  int k0 = ch * 576;             // 9 tiles of 64

  int a_row = (w << 2) + (lane >> 4);
  int a_g = lane & 15;
  int a_gx = (a_g & 8) | ((a_g ^ a_row) & 7);
  const float* aSrc = adj + (size_t)(n0 + a_row) * 4000 + (a_gx << 2);
  const float* aSrcT = adj + (size_t)(n0 + a_row) * 4000 + 3968 +
                       ((a_g < 8) ? (((a_g ^ a_row) & 7) << 2) : 0);
  const unsigned short* bSrc[6];
  int bj[6];
#pragma unroll
  for (int q = 0; q < 6; q++) {
    int ib = w * 6 + q;
    int j = ib * 8 + (lane >> 3);
    int g = lane & 7;
    bj[q] = ib * 512;
    bSrc[q] = XBT + (size_t)j * 4032 + ((g ^ (j & 7)) << 3);
  }

#define STAGE_K2(kt, buf)                                                      \
  {                                                                            \
    __builtin_amdgcn_global_load_lds((const GLOBAL_AS unsigned int*)(aSrc + (kt)), \
        (LDS_AS unsigned int*)&Ab[(buf)][w * 256], 16, 0, 0);                  \
    _Pragma("unroll")                                                          \
    for (int q = 0; q < 6; q++)                                                \
      __builtin_amdgcn_global_load_lds((const GLOBAL_AS unsigned int*)(bSrc[q] + (kt)), \
          (LDS_AS unsigned int*)&Bb[(buf)][bj[q]], 16, 0, 0);                  \
  }
#define STAGE_K2T(buf)                                                         \
  {                                                                            \
    __builtin_amdgcn_global_load_lds((const GLOBAL_AS unsigned int*)(aSrcT),   \
        (LDS_AS unsigned int*)&Ab[(buf)][w * 256], 16, 0, 0);                  \
    _Pragma("unroll")                                                          \
    for (int q = 0; q < 6; q++)                                                \
      __builtin_amdgcn_global_load_lds((const GLOBAL_AS unsigned int*)(bSrc[q] + 3968), \
          (LDS_AS unsigned int*)&Bb[(buf)][bj[q]], 16, 0, 0);                  \
  }

  floatx4 acc[3];
  acc[0] = acc[1] = acc[2] = floatx4{0.f, 0.f, 0.f, 0.f};
  int rowA = l15;
  int xA = (rowA & 7) << 2;
  int jb[3], xB[3];
#pragma unroll
  for (int ct = 0; ct < 3; ct++) {
    int j = w * 48 + ct * 16 + l15;
    jb[ct] = j * 64;
    xB[ct] = (j & 7) << 3;
  }

  STAGE_K2(k0, 0);
  for (int i = 0; i < 9; i++) {
    int cur = i & 1;
    int gtile = ch * 9 + i;
    if (i < 8) {
      if (ch * 9 + i + 1 == 62) { STAGE_K2T(cur ^ 1); }
      else                      { STAGE_K2(k0 + (i + 1) * 64, cur ^ 1); }
      asm volatile("s_waitcnt vmcnt(7)" ::: "memory");
    } else {
      asm volatile("s_waitcnt vmcnt(0)" ::: "memory");
    }
    __builtin_amdgcn_s_barrier();
    asm volatile("" ::: "memory");
    int kslim = (gtile == 62) ? 1 : 2;
    for (int ks = 0; ks < kslim; ks++) {
      int k0i = ks * 32 + kg * 8;
      float4 u = *reinterpret_cast<const float4*>(&Ab[cur][rowA * 64 + (k0i ^ xA)]);
      float4 v = *reinterpret_cast<const float4*>(&Ab[cur][rowA * 64 + ((k0i + 4) ^ xA)]);
      short8v af;
      af[0] = f2bf(u.x); af[1] = f2bf(u.y); af[2] = f2bf(u.z); af[3] = f2bf(u.w);
      af[4] = f2bf(v.x); af[5] = f2bf(v.y); af[6] = f2bf(v.z); af[7] = f2bf(v.w);
#pragma unroll
      for (int ct = 0; ct < 3; ct++) {
        short8v bf = *reinterpret_cast<const short8v*>(&Bb[cur][jb[ct] + (k0i ^ xB[ct])]);
        acc[ct] = __builtin_amdgcn_mfma_f32_16x16x32_bf16(af, bf, acc[ct], 0, 0, 0);
      }
    }
    __builtin_amdgcn_s_barrier();
  }
#pragma unroll
  for (int ct = 0; ct < 3; ct++) {
    int j = w * 48 + ct * 16 + l15;
#pragma unroll
    for (int e = 0; e < 4; e++) {
      int n = n0 + kg * 4 + e;
      XGP[(size_t)ch * 768000 + (size_t)j * 4000 + n] = acc[ct][e];
    }
  }
}

// ---------------- K3: persistent LSTM, single-mult f16 MFMA, 32 rows/block
__global__ __launch_bounds__(256, 3) void lstm_kernel(
    const float* __restrict__ XGP, const unsigned short* __restrict__ Wt2,
    const float* __restrict__ W_gcn, const float* __restrict__ b_gcn,
    const float* __restrict__ b_ih, const float* __restrict__ b_hh,
    const float* __restrict__ W_out, const float* __restrict__ b_out,
    float* __restrict__ out) {
  __shared__ unsigned short A[32 * 128];  // [row][k] f16, XOR-swizzled
  __shared__ float xga[24 * 32];
  __shared__ float red[8 * 32];

  int tid = threadIdx.x;
  int w = tid >> 6, lane = tid & 63, l15 = lane & 15, kg = lane >> 4;
  int r0 = blockIdx.x * 32;
  int hidx = w * 16 + l15;

  half8 wf[4][4];
#pragma unroll
  for (int ct = 0; ct < 4; ct++) {
    int j = ct * 64 + hidx;
#pragma unroll
    for (int ks = 0; ks < 4; ks++)
      wf[ct][ks] = *reinterpret_cast<const half8*>(&Wt2[j * 128 + ks * 32 + kg * 8]);
  }
  float bI = b_ih[hidx] + b_hh[hidx];
  float bF = b_ih[64 + hidx] + b_hh[64 + hidx];
  float bG = b_ih[128 + hidx] + b_hh[128 + hidx];
  float bO = b_ih[192 + hidx] + b_hh[192 + hidx];
  float wg0 = W_gcn[2 * hidx], wg1 = W_gcn[2 * hidx + 1], bg = b_gcn[hidx];

  for (int i = tid; i < 32 * 128 / 2; i += 256)
    reinterpret_cast<unsigned int*>(A)[i] = 0u;
  for (int i = tid; i < 24 * 32; i += 256) {
    int row = i & 31, tc = i >> 5;
    int g = r0 + row;
    int b = g / 4000, n = g - b * 4000;
    size_t base = (size_t)(b * 24 + tc) * 4000 + n;
    float s = 0.f;
#pragma unroll
    for (int chh = 0; chh < 7; chh++) s += XGP[(size_t)chh * 768000 + base];
    xga[i] = s;
  }
  float creg[8];
#pragma unroll
  for (int i = 0; i < 8; i++) creg[i] = 0.f;
  __syncthreads();

  for (int t = 0; t < 12; t++) {
#pragma unroll
    for (int half = 0; half < 2; half++)
#pragma unroll
      for (int rr = 0; rr < 4; rr++) {
        int row = half * 16 + kg * 4 + rr;
        float xg0 = xga[(2 * t) * 32 + row];
        float xg1 = xga[(2 * t + 1) * 32 + row];
        float gv = fmaxf(xg0 * wg0 + xg1 * wg1 + bg, 0.f);
        _Float16 hv = (_Float16)gv;
        A[row * 128 + (hidx ^ ((row & 7) << 3))] = __builtin_bit_cast(unsigned short, hv);
      }
    __syncthreads();

    floatx4 acc[2][4];
#pragma unroll
    for (int rt = 0; rt < 2; rt++)
#pragma unroll
      for (int ct = 0; ct < 4; ct++) acc[rt][ct] = floatx4{0.f, 0.f, 0.f, 0.f};
#pragma unroll
    for (int rt = 0; rt < 2; rt++) {
      int row = rt * 16 + l15;
      int xr = (row & 7) << 3;
      half8 af[4];
#pragma unroll
      for (int ks = 0; ks < 4; ks++)
        af[ks] = *reinterpret_cast<const half8*>(&A[row * 128 + ((ks * 32 + kg * 8) ^ xr)]);
#pragma unroll
      for (int ks = 0; ks < 4; ks++)
#pragma unroll
        for (int ct = 0; ct < 4; ct++)
          acc[rt][ct] = __builtin_amdgcn_mfma_f32_16x16x32_f16(
              af[ks], wf[ct][ks], acc[rt][ct], 0, 0, 0);
    }
    __syncthreads();

#pragma unroll
    for (int rt = 0; rt < 2; rt++)
#pragma unroll
      for (int e = 0; e < 4; e++) {
        int row = rt * 16 + kg * 4 + e;
        float gi = acc[rt][0][e] + bI;
        float gf = acc[rt][1][e] + bF;
        float gg = acc[rt][2][e] + bG;
        float go = acc[rt][3][e] + bO;
        float c = sigf(gf) * creg[rt * 4 + e] + sigf(gi) * tanhf_(gg);
        creg[rt * 4 + e] = c;
        float h = sigf(go) * tanhf_(c);
        _Float16 hv = (_Float16)h;
        A[row * 128 + ((64 + hidx) ^ ((row & 7) << 3))] = __builtin_bit_cast(unsigned short, hv);
      }
  }
  __syncthreads();

  {
    int rg = tid & 31, kq = tid >> 5;
    float partial = 0.f;
#pragma unroll
    for (int i = 0; i < 8; i++) {
      int k = kq * 8 + i;
      float hv = (float)__builtin_bit_cast(
          _Float16, A[rg * 128 + ((64 + k) ^ ((rg & 7) << 3))]);
      partial += hv * W_out[k];
    }
    red[kq * 32 + rg] = partial;
  }
  __syncthreads();
  if (tid < 32) {
    float s = b_out[0];
#pragma unroll
    for (int i = 0; i < 8; i++) s += red[i * 32 + tid];
    out[r0 + tid] = s;
  }
}

extern "C" void kernel_launch(void* const* d_in, const int* in_sizes, int n_in,
                              void* d_out, int out_size, void* d_ws, size_t ws_size,
                              hipStream_t stream) {
  const float* x     = (const float*)d_in[0];
  const float* adj   = (const float*)d_in[1];
  const float* W_gcn = (const float*)d_in[2];
  const float* b_gcn = (const float*)d_in[3];
  const float* W_ih  = (const float*)d_in[4];
  const float* W_hh  = (const float*)d_in[5];
  const float* b_ih  = (const float*)d_in[6];
  const float* b_hh  = (const float*)d_in[7];
  const float* W_out = (const float*)d_in[8];
  const float* b_out = (const float*)d_in[9];
  float* outp = (float*)d_out;

  float* XGP = (float*)d_ws;                                       // 7*768000 f32 = 21,504,000 B
  unsigned short* XBT = (unsigned short*)((char*)d_ws + 21504000); // 192*4032 bf16
  unsigned short* Wt2 = (unsigned short*)((char*)d_ws + 23052288); // 256*128 f16

  prep_kernel<<<394, 256, 0, stream>>>(x, W_ih, W_hh, XBT, Wt2);
  gcn_gemm_kernel<<<1750, 256, 0, stream>>>(adj, XBT, XGP);
  lstm_kernel<<<1000, 256, 0, stream>>>(XGP, Wt2, W_gcn, b_gcn, b_ih, b_hh,
                                        W_out, b_out, outp);
}